// Round 18
// baseline (136.311 us; speedup 1.0000x reference)
//
#include <hip/hip_runtime.h>

typedef unsigned short u16;
typedef unsigned int   u32;
typedef short bf16x8 __attribute__((ext_vector_type(8)));
typedef float f32x4  __attribute__((ext_vector_type(4)));
typedef float f32x2  __attribute__((ext_vector_type(2)));

#define MFMA(a,b,c) __builtin_amdgcn_mfma_f32_16x16x32_bf16((a),(b),(c),0,0,0)
#define MB (1u<<20)

__device__ __forceinline__ u16 f2bf(float x) {
  u32 u = __builtin_bit_cast(u32, x);
  u32 r = (u + 0x7FFFu + ((u >> 16) & 1u)) >> 16;   // RNE
  return (u16)r;
}
__device__ __forceinline__ float bf2f(u16 b) {
  u32 u = ((u32)b) << 16;
  return __builtin_bit_cast(float, u);
}
__device__ __forceinline__ void async16(void* lds, const void* g) {
  __builtin_amdgcn_global_load_lds(
      (const __attribute__((address_space(1))) u32*)g,
      (__attribute__((address_space(3))) u32*)lds, 16, 0, 0);
}

// ---------------------------------------------------------------------------
// ws layout (MB):
//  0 Xq_hi | 4 Xq_lo | 8 Xk_hi | 12 Xk_lo | 16 Xv_hi | (20 unused)
// 24 Wq_hi | 26 Wq_lo | 28 Wk_hi | 30 Wk_lo | 32 Wv_hi | 36 Wo_hi
// 40 Qf_hi | 44 Qf_lo | 48 Kf_hi | 52 Kf_lo | 56 Vf_hi (fragment-major,
//                                             written by proj z=2 directly)
// reuse after attn:  8 At_hi
//
// FRAGMENT-MAJOR layouts (r10, verified +55µs): attn fragment loads are
// base + lane*16B, fully coalesced.
// Precision plan: Q,K hi/lo 3-product; V, At, Wo bf16-hi only.
// r12: V prefetch post-bisection (pre-bisection spilled, WRITE 4->74MB).
// r14: (512,6) = 3 blocks/CU is the occupancy optimum ((512,8) spills).
// r15: vtrans fused into proj z=2 epilogue.  r16: interleaved A/B bisection.
// r17: seeded bisection (probe m-2.5, bracket [m-8,m]); final 3 blocks/CU.
// r18: PAIRED chunk loop - 4 rotating chunk buffers, one barrier per TWO
// chunks (8 -> 4 barrier rounds); K prefetch 2 deep via kfA/kfB.
// ---------------------------------------------------------------------------

// ---------------- presplit: f32 -> (hi[,lo]) bf16 --------------------------
__global__ __launch_bounds__(256) void presplit_kernel(
    const float* q, const float* k, const float* v,
    const float* wq, const float* wk, const float* wv, const float* wo,
    char* ws)
{
  int y = blockIdx.y;
  const float* srcs[7] = {q, k, v, wq, wk, wv, wo};
  size_t hoffv = (y < 3) ? (size_t)y * (8*MB) : (size_t)(24*MB) + (size_t)(y-3) * (4*MB);
  size_t loffv = hoffv + ((y < 3) ? (size_t)(4*MB) : (size_t)(2*MB));
  bool wlo = (y == 0) || (y == 1) || (y == 3) || (y == 4);
  int n = (y < 3) ? (2*1024*1024) : (1024*1024);
  int idx = (blockIdx.x * 256 + threadIdx.x) * 4;
  if (idx >= n) return;
  float4 x = *(const float4*)(srcs[y] + idx);
  ushort4 hv; hv.x = f2bf(x.x); hv.y = f2bf(x.y); hv.z = f2bf(x.z); hv.w = f2bf(x.w);
  *(ushort4*)(ws + hoffv + (size_t)idx * 2) = hv;
  if (wlo) {
    ushort4 lv;
    lv.x = f2bf(x.x - bf2f(hv.x)); lv.y = f2bf(x.y - bf2f(hv.y));
    lv.z = f2bf(x.z - bf2f(hv.z)); lv.w = f2bf(x.w - bf2f(hv.w));
    *(ushort4*)(ws + loffv + (size_t)idx * 2) = lv;
  }
}

// ---------------- proj GEMM  C = A @ B^T  (128x128 tile, 8 waves) ----------
// M=2048 N=1024 K=1024.  Grid: bids 0..255 = HEAVY (z=bid&1, 3-product),
// bids 256..383 = LIGHT (z=2, hi-only -> writes Vf fragment-major directly).
#define PA_H 0
#define PA_L 16384
#define PB_H 32768
#define PB_L 49152
#define PROJ_LDS 65536

__global__ __launch_bounds__(512, 4) void proj_kernel(char* ws,
    const float* bq, const float* bk, const float* bv)
{
  __shared__ __align__(16) char smem[PROJ_LDS];
  const int bid = blockIdx.x;
  const int z = (bid < 256) ? (bid & 1) : 2;
  const int tile = (bid < 256) ? (bid >> 1) : (bid - 256);
  const bool split = (z < 2);
  const u16* Ah = (const u16*)(ws + (size_t)z*(8*MB));
  const u16* Al = (const u16*)(ws + (size_t)z*(8*MB) + 4*MB);
  const u16* Bh = (const u16*)(ws + (size_t)(24*MB) + (size_t)z*(4*MB));
  const u16* Bl = (const u16*)(ws + (size_t)(24*MB) + (size_t)z*(4*MB) + 2*MB);
  u16* Oh = (u16*)(ws + (size_t)(40*MB) + (size_t)z*(8*MB));
  u16* Ol = (u16*)(ws + (size_t)(40*MB) + (size_t)z*(8*MB) + 4*MB);
  const float* bias = (z == 0) ? bq : ((z == 1) ? bk : bv);
  const float scale = (z == 0) ? 0.125f : 1.0f;   // fold 1/sqrt(dh) into Q

  const int t = threadIdx.x, w = t >> 6, lane = t & 63;
  const int l15 = lane & 15, l4 = lane >> 4;
  const int m0 = (tile >> 3) * 128;
  const int n0 = (tile & 7) * 128;
  const int mw = (w >> 2) * 64, nw = (w & 3) * 32;

  f32x4 acc[4][2];
  const f32x4 z4 = {0.f, 0.f, 0.f, 0.f};
  #pragma unroll
  for (int i = 0; i < 4; ++i)
    #pragma unroll
    for (int j = 0; j < 2; ++j) acc[i][j] = z4;

  for (int kt = 0; kt < 16; ++kt) {
    __syncthreads();
    #pragma unroll
    for (int i = 0; i < 2; ++i) {
      int chunk = w*128 + i*64 + lane;          // 1024 chunks of 16B per tile
      int row = chunk >> 3, seg = chunk & 7;
      int ss = seg ^ (row & 7);
      size_t ga = (size_t)(m0 + row) * 1024 + kt*64 + ss*8;
      size_t gb = (size_t)(n0 + row) * 1024 + kt*64 + ss*8;
      async16(smem + PA_H + chunk*16, Ah + ga);
      async16(smem + PB_H + chunk*16, Bh + gb);
      if (split) {
        async16(smem + PA_L + chunk*16, Al + ga);
        async16(smem + PB_L + chunk*16, Bl + gb);
      }
    }
    __syncthreads();
    #pragma unroll
    for (int kf = 0; kf < 2; ++kf) {
      bf16x8 avh[4], avl[4], bvh[2], bvl[2];
      #pragma unroll
      for (int mf = 0; mf < 4; ++mf) {
        int row = mw + mf*16 + l15;
        int ks = kf*4 + l4;
        int off = row*128 + ((ks ^ (row & 7)) << 4);
        avh[mf] = *(const bf16x8*)(smem + PA_H + off);
        if (split) avl[mf] = *(const bf16x8*)(smem + PA_L + off);
      }
      #pragma unroll
      for (int nf = 0; nf < 2; ++nf) {
        int row = nw + nf*16 + l15;
        int ks = kf*4 + l4;
        int off = row*128 + ((ks ^ (row & 7)) << 4);
        bvh[nf] = *(const bf16x8*)(smem + PB_H + off);
        if (split) bvl[nf] = *(const bf16x8*)(smem + PB_L + off);
      }
      #pragma unroll
      for (int mf = 0; mf < 4; ++mf)
        #pragma unroll
        for (int nf = 0; nf < 2; ++nf) {
          acc[mf][nf] = MFMA(avh[mf], bvh[nf], acc[mf][nf]);
          if (split) {
            acc[mf][nf] = MFMA(avh[mf], bvl[nf], acc[mf][nf]);
            acc[mf][nf] = MFMA(avl[mf], bvh[nf], acc[mf][nf]);
          }
        }
    }
  }
  #pragma unroll
  for (int mf = 0; mf < 4; ++mf)
    #pragma unroll
    for (int nf = 0; nf < 2; ++nf) {
      int colg = n0 + nw + nf*16 + l15;
      float bb = bias[colg];
      #pragma unroll
      for (int r = 0; r < 4; ++r) {
        int rowg = m0 + mw + mf*16 + l4*4 + r;
        float val = (acc[mf][nf][r] + bb) * scale;
        u16 hb = f2bf(val);
        int bq_ = rowg >> 10, s = rowg & 1023;
        int hh = colg >> 6, d = colg & 63;
        int bh2 = bq_*16 + hh;
        if (z == 2) {
          // Vf fragment-major (r15: replaces vtrans)
          int fb = d >> 4, l15v = d & 15;
          int half = s >> 9, ks = (s >> 5) & 15, l4v = (s >> 3) & 3, de = s & 7;
          size_t o = ((size_t)(((bh2*4 + fb)*2 + half)*16 + ks))*512
                     + (l4v*16 + l15v)*8 + de;
          Oh[o] = hb;
        } else {
          int reg = d >> 5, l4s = (d & 31) >> 3, de = d & 7;
          int lane2 = l4s*16 + (s & 15);
          size_t o;
          if (z == 0) o = ((size_t)((bh2*64 + (s >> 4))*2 + reg))*512 + lane2*8 + de;
          else        o = ((size_t)(((bh2*8 + (s >> 7))*8 + ((s >> 4) & 7))*2 + reg))*512 + lane2*8 + de;
          Oh[o] = hb;
          Ol[o] = f2bf(val - bf2f(hb));
        }
      }
    }
}

// ---------------- final GEMM  out = At @ Wo^T + bo  (hi-only, f32 out) -----
// 64x64 tiles, grid 512; 3 blocks/CU (r17).
#define FB_OFF 8192
#define FIN_LDS 16384

__global__ __launch_bounds__(256, 3) void final_kernel(char* ws, const float* bo, float* out)
{
  __shared__ __align__(16) char smem[FIN_LDS];
  const u16* Ah = (const u16*)(ws + (size_t)(8*MB));
  const u16* Bh = (const u16*)(ws + (size_t)(36*MB));
  const int t = threadIdx.x, w = t >> 6, lane = t & 63;
  const int l15 = lane & 15, l4 = lane >> 4;
  const int m0 = (blockIdx.x >> 4) * 64;
  const int n0 = (blockIdx.x & 15) * 64;
  const int mw = (w >> 1) * 32, nw = (w & 1) * 32;

  f32x4 acc[2][2];
  const f32x4 z4 = {0.f, 0.f, 0.f, 0.f};
  #pragma unroll
  for (int i = 0; i < 2; ++i)
    #pragma unroll
    for (int j = 0; j < 2; ++j) acc[i][j] = z4;

  for (int kt = 0; kt < 16; ++kt) {
    __syncthreads();
    #pragma unroll
    for (int i = 0; i < 2; ++i) {             // A: 512 chunks, B: 512 chunks
      int chunk = t + i*256;
      int row = chunk >> 3, seg = chunk & 7;
      int ss = seg ^ (row & 7);
      async16(smem + chunk*16, Ah + (size_t)(m0 + row) * 1024 + kt*64 + ss*8);
      async16(smem + FB_OFF + chunk*16, Bh + (size_t)(n0 + row) * 1024 + kt*64 + ss*8);
    }
    __syncthreads();
    #pragma unroll
    for (int kf = 0; kf < 2; ++kf) {
      bf16x8 avh[2], bvh[2];
      #pragma unroll
      for (int mf = 0; mf < 2; ++mf) {
        int row = mw + mf*16 + l15;
        int ks = kf*4 + l4;
        avh[mf] = *(const bf16x8*)(smem + row*128 + ((ks ^ (row & 7)) << 4));
      }
      #pragma unroll
      for (int nf = 0; nf < 2; ++nf) {
        int row = nw + nf*16 + l15;
        int ks = kf*4 + l4;
        bvh[nf] = *(const bf16x8*)(smem + FB_OFF + row*128 + ((ks ^ (row & 7)) << 4));
      }
      #pragma unroll
      for (int mf = 0; mf < 2; ++mf)
        #pragma unroll
        for (int nf = 0; nf < 2; ++nf)
          acc[mf][nf] = MFMA(avh[mf], bvh[nf], acc[mf][nf]);
    }
  }
  #pragma unroll
  for (int mf = 0; mf < 2; ++mf)
    #pragma unroll
    for (int nf = 0; nf < 2; ++nf) {
      int colg = n0 + nw + nf*16 + l15;
      float bb = bo[colg];
      #pragma unroll
      for (int r = 0; r < 4; ++r) {
        int rowg = m0 + mw + mf*16 + l4*4 + r;
        out[(size_t)rowg * 1024 + colg] = acc[mf][nf][r] + bb;
      }
    }
}

// ---------------- attention: QK^T -> exact top-170 -> softmax -> PV --------
// Chunked-transpose design with FRAGMENT-MAJOR coalesced K/Q/V loads (r10).
// (512,6) = 3 blocks/CU.  r18: paired chunks, 4 rotating buffers, 4 barriers.
#define CB_STRIDE 528          // chunk buf row stride (132 words, +4 mod 32)
#define CB_SZ     8448         // 16 * 528
#define P_STRIDE  2064
#define PART_OFF  33024        // 16*2064 -> partials (4 KB); bufs overlay P
#define ATT_LDS   (PART_OFF + 4096)
#define KSEL 170

__global__ __launch_bounds__(512, 6) void attn_kernel(char* ws)
{
  __shared__ __align__(16) char smem[ATT_LDS];
  const u16* Qh  = (const u16*)(ws + (size_t)(40*MB));
  const u16* Ql  = (const u16*)(ws + (size_t)(44*MB));
  const u16* Kh  = (const u16*)(ws + (size_t)(48*MB));
  const u16* Kl  = (const u16*)(ws + (size_t)(52*MB));
  const u16* Vf  = (const u16*)(ws + (size_t)(56*MB));
  u16* Ath = (u16*)(ws + (size_t)(8*MB));

  int t = threadIdx.x, w = t >> 6, lane = t & 63;
  int l15 = lane & 15, l4 = lane >> 4;
  int bid = blockIdx.x;
  int logical = (bid & 7) * 256 + (bid >> 3);   // XCD swizzle: 4 bh per XCD
  int bh = logical >> 6, qt = logical & 63;
  int b = bh >> 4, h = bh & 15;
  int q0 = qt * 16;

  const f32x4 z4 = {0.f, 0.f, 0.f, 0.f};

  // ---- K frag loads: fully coalesced, base + lane*16B ---------------------
  bf16x8 kfA[4], kfB[4];
#define LOADKC2(DST, KC) do { \
    size_t kb2 = ((size_t)(((bh*8 + (KC))*8 + w)*2))*512 + lane*8; \
    DST[0] = *(const bf16x8*)(Kh + kb2); \
    DST[1] = *(const bf16x8*)(Kh + kb2 + 512); \
    DST[2] = *(const bf16x8*)(Kl + kb2); \
    DST[3] = *(const bf16x8*)(Kl + kb2 + 512); \
  } while (0)

  LOADKC2(kfA, 0);
  LOADKC2(kfB, 1);

  // ---- Q fragments (coalesced fragment-major) -----------------------------
  bf16x8 qfh[2], qfl[2];
  {
    size_t qb2 = ((size_t)((bh*64 + qt)*2))*512 + lane*8;
    qfh[0] = *(const bf16x8*)(Qh + qb2);
    qfh[1] = *(const bf16x8*)(Qh + qb2 + 512);
    qfl[0] = *(const bf16x8*)(Ql + qb2);
    qfl[1] = *(const bf16x8*)(Ql + qb2 + 512);
  }

  // 16x16 QK^T tile for chunk KC from frag set KARR -> buffer (KC&3)
#define QKCHUNK2(KARR, KC) do { \
    f32x4 a0 = z4, a1 = z4; \
    a0 = MFMA(qfh[0], KARR[0], a0); \
    a1 = MFMA(qfh[1], KARR[1], a1); \
    a0 = MFMA(qfl[0], KARR[0], a0); \
    a1 = MFMA(qfl[1], KARR[1], a1); \
    a0 = MFMA(qfh[0], KARR[2], a0); \
    a1 = MFMA(qfh[1], KARR[3], a1); \
    _Pragma("unroll") \
    for (int r_ = 0; r_ < 4; ++r_) \
      *(float*)(smem + ((KC) & 3)*CB_SZ + (l4*4 + r_)*CB_STRIDE + (w*16 + l15)*4) \
          = a0[r_] + a1[r_]; \
  } while (0)

  // ---- paired chunk loop: 2 chunks per barrier (r18) ----------------------
  // Aliasing: read(pair p) finishes before this wave's lgkmcnt(0) at
  // barrier(p+1); buffers (2p&3),(2p+1&3) are rewritten only at pair p+2,
  // i.e. after barrier(p+1) on every wave.  Safe.
  f32x2 va[8], vb[8];          // full score rows w and w+8
  #pragma unroll
  for (int p = 0; p < 4; ++p) {
    QKCHUNK2(kfA, 2*p);
    if (p < 3) LOADKC2(kfA, 2*p + 2);    // WAR on kfA: ordered after MFMAs
    QKCHUNK2(kfB, 2*p + 1);
    if (p < 3) LOADKC2(kfB, 2*p + 3);
    asm volatile("s_waitcnt lgkmcnt(0)" ::: "memory");
    __builtin_amdgcn_s_barrier();
    asm volatile("" ::: "memory");       // keep reads below the barrier
    va[2*p]   = *(const f32x2*)(smem + ((2*p) & 3)*CB_SZ + w*CB_STRIDE + lane*8);
    vb[2*p]   = *(const f32x2*)(smem + ((2*p) & 3)*CB_SZ + (w + 8)*CB_STRIDE + lane*8);
    va[2*p+1] = *(const f32x2*)(smem + ((2*p+1) & 3)*CB_SZ + w*CB_STRIDE + lane*8);
    vb[2*p+1] = *(const f32x2*)(smem + ((2*p+1) & 3)*CB_SZ + (w + 8)*CB_STRIDE + lane*8);
  }
  __syncthreads();   // all chunk reads done; P region (overlapping) now safe

  // ---- PV geometry (V loads issued late, after bisection) -----------------
  int f = w & 3, half = w >> 2;
  size_t vbase = ((size_t)(((bh*4 + f)*2 + half)*16))*512 + lane*8;
  bf16x8 vv[2][4];
#define LOADV(BUF, G) do { \
    _Pragma("unroll") \
    for (int j_ = 0; j_ < 4; ++j_) \
      vv[BUF][j_] = *(const bf16x8*)(Vf + vbase + (size_t)((G)*4 + j_)*512); \
    } while (0)

  // ---- dual-row exact top-170 + softmax (all in registers) ----------------
  {
    float mA = va[0][0], mB = vb[0][0];
    #pragma unroll
    for (int i = 0; i < 8; ++i)
      #pragma unroll
      for (int e = 0; e < 2; ++e) {
        mA = fmaxf(mA, va[i][e]);
        mB = fmaxf(mB, vb[i][e]);
      }
    #pragma unroll
    for (int off = 32; off > 0; off >>= 1) {
      mA = fmaxf(mA, __shfl_xor(mA, off));
      mB = fmaxf(mB, __shfl_xor(mB, off));
    }

    // r17: seeded probe at m-2.5 (scores ~N(0,1): 170th/1024 near m-2.2),
    // bracket [m-8, m] (clamp drops only weight<e^-8 keys, <=1e-3 absmax).
    // Then regula-falsi (to it=8) -> bisection, INTERLEAVED A/B.
    float loA = mA - 8.f, hiA = mA, cLoA = 1024.f, cHiA = 1.f;
    float loB = mB - 8.f, hiB = mB, cLoB = 1024.f, cHiB = 1.f;
    float thrA = 0.f, thrB = 0.f;
    bool fA = false, fB = false;
    {
      float tA = mA - 2.5f, tB = mB - 2.5f;
      int cA = 0, cB = 0;
      #pragma unroll
      for (int i = 0; i < 8; ++i)
        #pragma unroll
        for (int e = 0; e < 2; ++e) {
          cA += (int)__popcll(__ballot(va[i][e] >= tA));
          cB += (int)__popcll(__ballot(vb[i][e] >= tB));
        }
      if (cA == KSEL) { thrA = tA; fA = true; }
      else if (cA > KSEL) { loA = tA; cLoA = (float)cA; }
      else { hiA = tA; cHiA = (float)cA; }
      if (cB == KSEL) { thrB = tB; fB = true; }
      else if (cB > KSEL) { loB = tB; cLoB = (float)cB; }
      else { hiB = tB; cHiB = (float)cB; }
    }
    #pragma unroll 1
    for (int it = 0; it < 32 && !(fA && fB); ++it) {
      float gA, gB;
      if (it < 8) {
        gA = fminf(fmaxf((cLoA - (float)KSEL) / fmaxf(cLoA - cHiA, 1.f), 0.10f), 0.90f);
        gB = fminf(fmaxf((cLoB - (float)KSEL) / fmaxf(cLoB - cHiB, 1.f), 0.10f), 0.90f);
      } else {
        gA = 0.5f; gB = 0.5f;
      }
      float tA = loA + (hiA - loA) * gA;
      float tB = loB + (hiB - loB) * gB;
      if (!(tA > loA && tA < hiA)) { if (!fA) { thrA = loA; fA = true; } tA = loA; }
      if (!(tB > loB && tB < hiB)) { if (!fB) { thrB = loB; fB = true; } tB = loB; }
      int cA = 0, cB = 0;
      #pragma unroll
      for (int i = 0; i < 8; ++i)
        #pragma unroll
        for (int e = 0; e < 2; ++e) {
          cA += (int)__popcll(__ballot(va[i][e] >= tA));
          cB += (int)__popcll(__ballot(vb[i][e] >= tB));
        }
      if (!fA) {
        if (cA == KSEL) { thrA = tA; fA = true; }
        else if (cA > KSEL) { loA = tA; cLoA = (float)cA; }
        else { hiA = tA; cHiA = (float)cA; }
      }
      if (!fB) {
        if (cB == KSEL) { thrB = tB; fB = true; }
        else if (cB > KSEL) { loB = tB; cLoB = (float)cB; }
        else { hiB = tB; cHiB = (float)cB; }
      }
    }
    if (!fA) thrA = loA;
    if (!fB) thrB = loB;

    // V group 0 prefetch: hidden under exp/sum/pack below (16 VGPRs only)
    LOADV(0, 0);

    float sA = 0.f, sB = 0.f;
    #pragma unroll
    for (int i = 0; i < 8; ++i)
      #pragma unroll
      for (int e = 0; e < 2; ++e) {
        float xa = va[i][e], xb = vb[i][e];
        float ea = (xa >= thrA) ? __expf(xa - mA) : 0.f;
        float eb = (xb >= thrB) ? __expf(xb - mB) : 0.f;
        va[i][e] = ea; vb[i][e] = eb;
        sA += ea; sB += eb;
      }
    #pragma unroll
    for (int off = 32; off > 0; off >>= 1) {
      sA += __shfl_xor(sA, off);
      sB += __shfl_xor(sB, off);
    }
    float rA_ = 1.f / sA, rB_ = 1.f / sB;

    // P write: row w and w+8; col = i*128 + lane*2 (ushort2 per chunk)
    #pragma unroll
    for (int i = 0; i < 8; ++i) {
      u32 pwA = (u32)f2bf(va[i][0] * rA_) | ((u32)f2bf(va[i][1] * rA_) << 16);
      u32 pwB = (u32)f2bf(vb[i][0] * rB_) | ((u32)f2bf(vb[i][1] * rB_) << 16);
      *(u32*)(smem + w*P_STRIDE       + i*256 + lane*4) = pwA;
      *(u32*)(smem + (w + 8)*P_STRIDE + i*256 + lane*4) = pwB;
    }
  }
  __syncthreads();

  // ---- PV (V-hi only); group g+2 loaded during group g --------------------
  LOADV(1, 1);
  f32x4 ac0 = z4, ac1 = z4;
  #pragma unroll
  for (int g = 0; g < 4; ++g) {
    #pragma unroll
    for (int j = 0; j < 4; ++j) {
      int ksl = g*4 + j;
      bf16x8 pa = *(const bf16x8*)(smem + l15*P_STRIDE + (half*16 + ksl)*64 + l4*16);
      if (j & 1) ac1 = MFMA(pa, vv[g & 1][j], ac1);
      else       ac0 = MFMA(pa, vv[g & 1][j], ac0);
    }
    if (g == 0) LOADV(0, 2);
    if (g == 1) LOADV(1, 3);
  }
  f32x4 a = ac0 + ac1;

  if (half == 1)
    *(f32x4*)(smem + PART_OFF + (f*64 + lane)*16) = a;
  __syncthreads();
  if (half == 0) {
    f32x4 o4 = *(const f32x4*)(smem + PART_OFF + (f*64 + lane)*16);
    #pragma unroll
    for (int r = 0; r < 4; ++r) {
      float val = a[r] + o4[r];
      size_t o = (size_t)(b*1024 + q0 + l4*4 + r) * 1024 + h*64 + f*16 + l15;
      Ath[o] = f2bf(val);
    }
  }
}

// ---------------------------------------------------------------------------
extern "C" void kernel_launch(void* const* d_in, const int* in_sizes, int n_in,
                              void* d_out, int out_size, void* d_ws, size_t ws_size,
                              hipStream_t stream)
{
  const float* q  = (const float*)d_in[0];
  const float* k  = (const float*)d_in[1];
  const float* v  = (const float*)d_in[2];
  const float* wq = (const float*)d_in[3];
  const float* bq = (const float*)d_in[4];
  const float* wk = (const float*)d_in[5];
  const float* bk = (const float*)d_in[6];
  const float* wv = (const float*)d_in[7];
  const float* bv = (const float*)d_in[8];
  const float* wo = (const float*)d_in[9];
  const float* bo = (const float*)d_in[10];
  float* out = (float*)d_out;
  char* ws = (char*)d_ws;
  if (ws_size < (64ull << 20)) return;  // need 64 MB scratch

  presplit_kernel<<<dim3(2048, 7), 256, 0, stream>>>(q, k, v, wq, wk, wv, wo, ws);
  proj_kernel<<<384, 512, 0, stream>>>(ws, bq, bk, bv);
  attn_kernel<<<2048, 512, 0, stream>>>(ws);
  final_kernel<<<512, 256, 0, stream>>>(ws, bo, out);
}

// Round 19
// 129.321 us; speedup vs baseline: 1.0540x; 1.0540x over previous
//
#include <hip/hip_runtime.h>

typedef unsigned short u16;
typedef unsigned int   u32;
typedef short bf16x8 __attribute__((ext_vector_type(8)));
typedef float f32x4  __attribute__((ext_vector_type(4)));
typedef float f32x2  __attribute__((ext_vector_type(2)));

#define MFMA(a,b,c) __builtin_amdgcn_mfma_f32_16x16x32_bf16((a),(b),(c),0,0,0)
#define MB (1u<<20)

__device__ __forceinline__ u16 f2bf(float x) {
  u32 u = __builtin_bit_cast(u32, x);
  u32 r = (u + 0x7FFFu + ((u >> 16) & 1u)) >> 16;   // RNE
  return (u16)r;
}
__device__ __forceinline__ float bf2f(u16 b) {
  u32 u = ((u32)b) << 16;
  return __builtin_bit_cast(float, u);
}
__device__ __forceinline__ void async16(void* lds, const void* g) {
  __builtin_amdgcn_global_load_lds(
      (const __attribute__((address_space(1))) u32*)g,
      (__attribute__((address_space(3))) u32*)lds, 16, 0, 0);
}

// ---------------------------------------------------------------------------
// ws layout (MB):
//  0 Xq_hi | 4 Xq_lo | 8 Xk_hi | 12 Xk_lo | 16 Xv_hi | (20 unused)
// 24 Wq_hi | 26 Wq_lo | 28 Wk_hi | 30 Wk_lo | 32 Wv_hi | 36 Wo_hi
// 40 Qf_hi | 44 Qf_lo | 48 Kf_hi | 52 Kf_lo | 56 Vf_hi (fragment-major,
//                                             written by proj z=2 directly)
// reuse after attn:  8 At_hi
//
// FRAGMENT-MAJOR layouts (r10, verified +55µs): attn fragment loads are
// base + lane*16B, fully coalesced.
// Precision plan: Q,K hi/lo 3-product; V, At, Wo bf16-hi only.
// r12: V prefetch post-bisection (pre-bisection spilled, WRITE 4->74MB).
// r14: (512,6) = 3 blocks/CU is the occupancy optimum ((512,8) spills).
// r15: vtrans fused into proj z=2 epilogue.  r16: interleaved A/B bisection.
// r17: seeded bisection (probe m-2.5, bracket [m-8,m]); final 3 blocks/CU.
// r19: REVERT r18's paired chunks (kfA+kfB spilled: FETCH 10->30MB, +9µs).
// Established: exactly ONE in-flight K frag set fits the register budget.
// ---------------------------------------------------------------------------

// ---------------- presplit: f32 -> (hi[,lo]) bf16 --------------------------
__global__ __launch_bounds__(256) void presplit_kernel(
    const float* q, const float* k, const float* v,
    const float* wq, const float* wk, const float* wv, const float* wo,
    char* ws)
{
  int y = blockIdx.y;
  const float* srcs[7] = {q, k, v, wq, wk, wv, wo};
  size_t hoffv = (y < 3) ? (size_t)y * (8*MB) : (size_t)(24*MB) + (size_t)(y-3) * (4*MB);
  size_t loffv = hoffv + ((y < 3) ? (size_t)(4*MB) : (size_t)(2*MB));
  bool wlo = (y == 0) || (y == 1) || (y == 3) || (y == 4);
  int n = (y < 3) ? (2*1024*1024) : (1024*1024);
  int idx = (blockIdx.x * 256 + threadIdx.x) * 4;
  if (idx >= n) return;
  float4 x = *(const float4*)(srcs[y] + idx);
  ushort4 hv; hv.x = f2bf(x.x); hv.y = f2bf(x.y); hv.z = f2bf(x.z); hv.w = f2bf(x.w);
  *(ushort4*)(ws + hoffv + (size_t)idx * 2) = hv;
  if (wlo) {
    ushort4 lv;
    lv.x = f2bf(x.x - bf2f(hv.x)); lv.y = f2bf(x.y - bf2f(hv.y));
    lv.z = f2bf(x.z - bf2f(hv.z)); lv.w = f2bf(x.w - bf2f(hv.w));
    *(ushort4*)(ws + loffv + (size_t)idx * 2) = lv;
  }
}

// ---------------- proj GEMM  C = A @ B^T  (128x128 tile, 8 waves) ----------
// M=2048 N=1024 K=1024.  Grid: bids 0..255 = HEAVY (z=bid&1, 3-product),
// bids 256..383 = LIGHT (z=2, hi-only -> writes Vf fragment-major directly).
#define PA_H 0
#define PA_L 16384
#define PB_H 32768
#define PB_L 49152
#define PROJ_LDS 65536

__global__ __launch_bounds__(512, 4) void proj_kernel(char* ws,
    const float* bq, const float* bk, const float* bv)
{
  __shared__ __align__(16) char smem[PROJ_LDS];
  const int bid = blockIdx.x;
  const int z = (bid < 256) ? (bid & 1) : 2;
  const int tile = (bid < 256) ? (bid >> 1) : (bid - 256);
  const bool split = (z < 2);
  const u16* Ah = (const u16*)(ws + (size_t)z*(8*MB));
  const u16* Al = (const u16*)(ws + (size_t)z*(8*MB) + 4*MB);
  const u16* Bh = (const u16*)(ws + (size_t)(24*MB) + (size_t)z*(4*MB));
  const u16* Bl = (const u16*)(ws + (size_t)(24*MB) + (size_t)z*(4*MB) + 2*MB);
  u16* Oh = (u16*)(ws + (size_t)(40*MB) + (size_t)z*(8*MB));
  u16* Ol = (u16*)(ws + (size_t)(40*MB) + (size_t)z*(8*MB) + 4*MB);
  const float* bias = (z == 0) ? bq : ((z == 1) ? bk : bv);
  const float scale = (z == 0) ? 0.125f : 1.0f;   // fold 1/sqrt(dh) into Q

  const int t = threadIdx.x, w = t >> 6, lane = t & 63;
  const int l15 = lane & 15, l4 = lane >> 4;
  const int m0 = (tile >> 3) * 128;
  const int n0 = (tile & 7) * 128;
  const int mw = (w >> 2) * 64, nw = (w & 3) * 32;

  f32x4 acc[4][2];
  const f32x4 z4 = {0.f, 0.f, 0.f, 0.f};
  #pragma unroll
  for (int i = 0; i < 4; ++i)
    #pragma unroll
    for (int j = 0; j < 2; ++j) acc[i][j] = z4;

  for (int kt = 0; kt < 16; ++kt) {
    __syncthreads();
    #pragma unroll
    for (int i = 0; i < 2; ++i) {
      int chunk = w*128 + i*64 + lane;          // 1024 chunks of 16B per tile
      int row = chunk >> 3, seg = chunk & 7;
      int ss = seg ^ (row & 7);
      size_t ga = (size_t)(m0 + row) * 1024 + kt*64 + ss*8;
      size_t gb = (size_t)(n0 + row) * 1024 + kt*64 + ss*8;
      async16(smem + PA_H + chunk*16, Ah + ga);
      async16(smem + PB_H + chunk*16, Bh + gb);
      if (split) {
        async16(smem + PA_L + chunk*16, Al + ga);
        async16(smem + PB_L + chunk*16, Bl + gb);
      }
    }
    __syncthreads();
    #pragma unroll
    for (int kf = 0; kf < 2; ++kf) {
      bf16x8 avh[4], avl[4], bvh[2], bvl[2];
      #pragma unroll
      for (int mf = 0; mf < 4; ++mf) {
        int row = mw + mf*16 + l15;
        int ks = kf*4 + l4;
        int off = row*128 + ((ks ^ (row & 7)) << 4);
        avh[mf] = *(const bf16x8*)(smem + PA_H + off);
        if (split) avl[mf] = *(const bf16x8*)(smem + PA_L + off);
      }
      #pragma unroll
      for (int nf = 0; nf < 2; ++nf) {
        int row = nw + nf*16 + l15;
        int ks = kf*4 + l4;
        int off = row*128 + ((ks ^ (row & 7)) << 4);
        bvh[nf] = *(const bf16x8*)(smem + PB_H + off);
        if (split) bvl[nf] = *(const bf16x8*)(smem + PB_L + off);
      }
      #pragma unroll
      for (int mf = 0; mf < 4; ++mf)
        #pragma unroll
        for (int nf = 0; nf < 2; ++nf) {
          acc[mf][nf] = MFMA(avh[mf], bvh[nf], acc[mf][nf]);
          if (split) {
            acc[mf][nf] = MFMA(avh[mf], bvl[nf], acc[mf][nf]);
            acc[mf][nf] = MFMA(avl[mf], bvh[nf], acc[mf][nf]);
          }
        }
    }
  }
  #pragma unroll
  for (int mf = 0; mf < 4; ++mf)
    #pragma unroll
    for (int nf = 0; nf < 2; ++nf) {
      int colg = n0 + nw + nf*16 + l15;
      float bb = bias[colg];
      #pragma unroll
      for (int r = 0; r < 4; ++r) {
        int rowg = m0 + mw + mf*16 + l4*4 + r;
        float val = (acc[mf][nf][r] + bb) * scale;
        u16 hb = f2bf(val);
        int bq_ = rowg >> 10, s = rowg & 1023;
        int hh = colg >> 6, d = colg & 63;
        int bh2 = bq_*16 + hh;
        if (z == 2) {
          // Vf fragment-major (r15: replaces vtrans)
          int fb = d >> 4, l15v = d & 15;
          int half = s >> 9, ks = (s >> 5) & 15, l4v = (s >> 3) & 3, de = s & 7;
          size_t o = ((size_t)(((bh2*4 + fb)*2 + half)*16 + ks))*512
                     + (l4v*16 + l15v)*8 + de;
          Oh[o] = hb;
        } else {
          int reg = d >> 5, l4s = (d & 31) >> 3, de = d & 7;
          int lane2 = l4s*16 + (s & 15);
          size_t o;
          if (z == 0) o = ((size_t)((bh2*64 + (s >> 4))*2 + reg))*512 + lane2*8 + de;
          else        o = ((size_t)(((bh2*8 + (s >> 7))*8 + ((s >> 4) & 7))*2 + reg))*512 + lane2*8 + de;
          Oh[o] = hb;
          Ol[o] = f2bf(val - bf2f(hb));
        }
      }
    }
}

// ---------------- final GEMM  out = At @ Wo^T + bo  (hi-only, f32 out) -----
// 64x64 tiles, grid 512; 3 blocks/CU (r17).
#define FB_OFF 8192
#define FIN_LDS 16384

__global__ __launch_bounds__(256, 3) void final_kernel(char* ws, const float* bo, float* out)
{
  __shared__ __align__(16) char smem[FIN_LDS];
  const u16* Ah = (const u16*)(ws + (size_t)(8*MB));
  const u16* Bh = (const u16*)(ws + (size_t)(36*MB));
  const int t = threadIdx.x, w = t >> 6, lane = t & 63;
  const int l15 = lane & 15, l4 = lane >> 4;
  const int m0 = (blockIdx.x >> 4) * 64;
  const int n0 = (blockIdx.x & 15) * 64;
  const int mw = (w >> 1) * 32, nw = (w & 1) * 32;

  f32x4 acc[2][2];
  const f32x4 z4 = {0.f, 0.f, 0.f, 0.f};
  #pragma unroll
  for (int i = 0; i < 2; ++i)
    #pragma unroll
    for (int j = 0; j < 2; ++j) acc[i][j] = z4;

  for (int kt = 0; kt < 16; ++kt) {
    __syncthreads();
    #pragma unroll
    for (int i = 0; i < 2; ++i) {             // A: 512 chunks, B: 512 chunks
      int chunk = t + i*256;
      int row = chunk >> 3, seg = chunk & 7;
      int ss = seg ^ (row & 7);
      async16(smem + chunk*16, Ah + (size_t)(m0 + row) * 1024 + kt*64 + ss*8);
      async16(smem + FB_OFF + chunk*16, Bh + (size_t)(n0 + row) * 1024 + kt*64 + ss*8);
    }
    __syncthreads();
    #pragma unroll
    for (int kf = 0; kf < 2; ++kf) {
      bf16x8 avh[2], bvh[2];
      #pragma unroll
      for (int mf = 0; mf < 2; ++mf) {
        int row = mw + mf*16 + l15;
        int ks = kf*4 + l4;
        avh[mf] = *(const bf16x8*)(smem + row*128 + ((ks ^ (row & 7)) << 4));
      }
      #pragma unroll
      for (int nf = 0; nf < 2; ++nf) {
        int row = nw + nf*16 + l15;
        int ks = kf*4 + l4;
        bvh[nf] = *(const bf16x8*)(smem + FB_OFF + row*128 + ((ks ^ (row & 7)) << 4));
      }
      #pragma unroll
      for (int mf = 0; mf < 2; ++mf)
        #pragma unroll
        for (int nf = 0; nf < 2; ++nf)
          acc[mf][nf] = MFMA(avh[mf], bvh[nf], acc[mf][nf]);
    }
  }
  #pragma unroll
  for (int mf = 0; mf < 2; ++mf)
    #pragma unroll
    for (int nf = 0; nf < 2; ++nf) {
      int colg = n0 + nw + nf*16 + l15;
      float bb = bo[colg];
      #pragma unroll
      for (int r = 0; r < 4; ++r) {
        int rowg = m0 + mw + mf*16 + l4*4 + r;
        out[(size_t)rowg * 1024 + colg] = acc[mf][nf][r] + bb;
      }
    }
}

// ---------------- attention: QK^T -> exact top-170 -> softmax -> PV --------
// Chunked-transpose design with FRAGMENT-MAJOR coalesced K/Q/V loads (r10).
// (512,6) = 3 blocks/CU.  Single K frag set, 8 barrier rounds (r17 verified).
#define CB_STRIDE 528          // chunk buf row stride (132 words, +4 mod 32)
#define CB_SZ     8448         // 16 * 528
#define P_STRIDE  2064
#define PART_OFF  33024        // 16*2064 -> partials (4 KB); P overlays dbuf
#define ATT_LDS   (PART_OFF + 4096)
#define KSEL 170

__global__ __launch_bounds__(512, 6) void attn_kernel(char* ws)
{
  __shared__ __align__(16) char smem[ATT_LDS];
  const u16* Qh  = (const u16*)(ws + (size_t)(40*MB));
  const u16* Ql  = (const u16*)(ws + (size_t)(44*MB));
  const u16* Kh  = (const u16*)(ws + (size_t)(48*MB));
  const u16* Kl  = (const u16*)(ws + (size_t)(52*MB));
  const u16* Vf  = (const u16*)(ws + (size_t)(56*MB));
  u16* Ath = (u16*)(ws + (size_t)(8*MB));

  int t = threadIdx.x, w = t >> 6, lane = t & 63;
  int l15 = lane & 15, l4 = lane >> 4;
  int bid = blockIdx.x;
  int logical = (bid & 7) * 256 + (bid >> 3);   // XCD swizzle: 4 bh per XCD
  int bh = logical >> 6, qt = logical & 63;
  int b = bh >> 4, h = bh & 15;
  int q0 = qt * 16;

  const f32x4 z4 = {0.f, 0.f, 0.f, 0.f};

  // ---- K frag loads: fully coalesced, base + lane*16B ---------------------
  bf16x8 kf[4];
#define LOADKC(KC) do { \
    size_t kb2 = ((size_t)(((bh*8 + (KC))*8 + w)*2))*512 + lane*8; \
    kf[0] = *(const bf16x8*)(Kh + kb2); \
    kf[1] = *(const bf16x8*)(Kh + kb2 + 512); \
    kf[2] = *(const bf16x8*)(Kl + kb2); \
    kf[3] = *(const bf16x8*)(Kl + kb2 + 512); \
  } while (0)

  LOADKC(0);

  // ---- Q fragments (coalesced fragment-major) -----------------------------
  bf16x8 qfh[2], qfl[2];
  {
    size_t qb2 = ((size_t)((bh*64 + qt)*2))*512 + lane*8;
    qfh[0] = *(const bf16x8*)(Qh + qb2);
    qfh[1] = *(const bf16x8*)(Qh + qb2 + 512);
    qfl[0] = *(const bf16x8*)(Ql + qb2);
    qfl[1] = *(const bf16x8*)(Ql + qb2 + 512);
  }

  // ---- chunk loop: MFMA -> prefetch next K -> write -> barrier -> read ----
  // Raw s_barrier with lgkmcnt(0) only: K loads stay in flight across the
  // barrier (waited at their MFMA use next iteration).
  f32x2 va[8], vb[8];          // full score rows w and w+8, filled per chunk
  #pragma unroll
  for (int kc = 0; kc < 8; ++kc) {
    f32x4 a0 = z4, a1 = z4;
    a0 = MFMA(qfh[0], kf[0], a0);
    a1 = MFMA(qfh[1], kf[1], a1);
    a0 = MFMA(qfl[0], kf[0], a0);
    a1 = MFMA(qfl[1], kf[1], a1);
    a0 = MFMA(qfh[0], kf[2], a0);
    a1 = MFMA(qfh[1], kf[3], a1);
    if (kc < 7) LOADKC(kc + 1);          // WAR on kf: ordered after MFMAs
    #pragma unroll
    for (int r_ = 0; r_ < 4; ++r_)
      *(float*)(smem + (kc & 1)*CB_SZ + (l4*4 + r_)*CB_STRIDE + (w*16 + l15)*4)
          = a0[r_] + a1[r_];
    asm volatile("s_waitcnt lgkmcnt(0)" ::: "memory");
    __builtin_amdgcn_s_barrier();
    asm volatile("" ::: "memory");       // keep reads below the barrier
    va[kc] = *(const f32x2*)(smem + (kc & 1)*CB_SZ + w*CB_STRIDE + lane*8);
    vb[kc] = *(const f32x2*)(smem + (kc & 1)*CB_SZ + (w + 8)*CB_STRIDE + lane*8);
  }
  __syncthreads();   // all chunk reads done; P region (overlapping) now safe

  // ---- PV geometry (V loads issued late, after bisection) -----------------
  int f = w & 3, half = w >> 2;
  size_t vbase = ((size_t)(((bh*4 + f)*2 + half)*16))*512 + lane*8;
  bf16x8 vv[2][4];
#define LOADV(BUF, G) do { \
    _Pragma("unroll") \
    for (int j_ = 0; j_ < 4; ++j_) \
      vv[BUF][j_] = *(const bf16x8*)(Vf + vbase + (size_t)((G)*4 + j_)*512); \
    } while (0)

  // ---- dual-row exact top-170 + softmax (all in registers) ----------------
  {
    float mA = va[0][0], mB = vb[0][0];
    #pragma unroll
    for (int i = 0; i < 8; ++i)
      #pragma unroll
      for (int e = 0; e < 2; ++e) {
        mA = fmaxf(mA, va[i][e]);
        mB = fmaxf(mB, vb[i][e]);
      }
    #pragma unroll
    for (int off = 32; off > 0; off >>= 1) {
      mA = fmaxf(mA, __shfl_xor(mA, off));
      mB = fmaxf(mB, __shfl_xor(mB, off));
    }

    // r17: seeded probe at m-2.5 (scores ~N(0,1): 170th/1024 near m-2.2),
    // bracket [m-8, m] (clamp drops only weight<e^-8 keys, <=1e-3 absmax).
    // Then regula-falsi (to it=8) -> bisection, INTERLEAVED A/B.
    float loA = mA - 8.f, hiA = mA, cLoA = 1024.f, cHiA = 1.f;
    float loB = mB - 8.f, hiB = mB, cLoB = 1024.f, cHiB = 1.f;
    float thrA = 0.f, thrB = 0.f;
    bool fA = false, fB = false;
    {
      float tA = mA - 2.5f, tB = mB - 2.5f;
      int cA = 0, cB = 0;
      #pragma unroll
      for (int i = 0; i < 8; ++i)
        #pragma unroll
        for (int e = 0; e < 2; ++e) {
          cA += (int)__popcll(__ballot(va[i][e] >= tA));
          cB += (int)__popcll(__ballot(vb[i][e] >= tB));
        }
      if (cA == KSEL) { thrA = tA; fA = true; }
      else if (cA > KSEL) { loA = tA; cLoA = (float)cA; }
      else { hiA = tA; cHiA = (float)cA; }
      if (cB == KSEL) { thrB = tB; fB = true; }
      else if (cB > KSEL) { loB = tB; cLoB = (float)cB; }
      else { hiB = tB; cHiB = (float)cB; }
    }
    #pragma unroll 1
    for (int it = 0; it < 32 && !(fA && fB); ++it) {
      float gA, gB;
      if (it < 8) {
        gA = fminf(fmaxf((cLoA - (float)KSEL) / fmaxf(cLoA - cHiA, 1.f), 0.10f), 0.90f);
        gB = fminf(fmaxf((cLoB - (float)KSEL) / fmaxf(cLoB - cHiB, 1.f), 0.10f), 0.90f);
      } else {
        gA = 0.5f; gB = 0.5f;
      }
      float tA = loA + (hiA - loA) * gA;
      float tB = loB + (hiB - loB) * gB;
      if (!(tA > loA && tA < hiA)) { if (!fA) { thrA = loA; fA = true; } tA = loA; }
      if (!(tB > loB && tB < hiB)) { if (!fB) { thrB = loB; fB = true; } tB = loB; }
      int cA = 0, cB = 0;
      #pragma unroll
      for (int i = 0; i < 8; ++i)
        #pragma unroll
        for (int e = 0; e < 2; ++e) {
          cA += (int)__popcll(__ballot(va[i][e] >= tA));
          cB += (int)__popcll(__ballot(vb[i][e] >= tB));
        }
      if (!fA) {
        if (cA == KSEL) { thrA = tA; fA = true; }
        else if (cA > KSEL) { loA = tA; cLoA = (float)cA; }
        else { hiA = tA; cHiA = (float)cA; }
      }
      if (!fB) {
        if (cB == KSEL) { thrB = tB; fB = true; }
        else if (cB > KSEL) { loB = tB; cLoB = (float)cB; }
        else { hiB = tB; cHiB = (float)cB; }
      }
    }
    if (!fA) thrA = loA;
    if (!fB) thrB = loB;

    // V group 0 prefetch: hidden under exp/sum/pack below (16 VGPRs only)
    LOADV(0, 0);

    float sA = 0.f, sB = 0.f;
    #pragma unroll
    for (int i = 0; i < 8; ++i)
      #pragma unroll
      for (int e = 0; e < 2; ++e) {
        float xa = va[i][e], xb = vb[i][e];
        float ea = (xa >= thrA) ? __expf(xa - mA) : 0.f;
        float eb = (xb >= thrB) ? __expf(xb - mB) : 0.f;
        va[i][e] = ea; vb[i][e] = eb;
        sA += ea; sB += eb;
      }
    #pragma unroll
    for (int off = 32; off > 0; off >>= 1) {
      sA += __shfl_xor(sA, off);
      sB += __shfl_xor(sB, off);
    }
    float rA_ = 1.f / sA, rB_ = 1.f / sB;

    // P write: row w and w+8; col = i*128 + lane*2 (ushort2 per chunk)
    #pragma unroll
    for (int i = 0; i < 8; ++i) {
      u32 pwA = (u32)f2bf(va[i][0] * rA_) | ((u32)f2bf(va[i][1] * rA_) << 16);
      u32 pwB = (u32)f2bf(vb[i][0] * rB_) | ((u32)f2bf(vb[i][1] * rB_) << 16);
      *(u32*)(smem + w*P_STRIDE       + i*256 + lane*4) = pwA;
      *(u32*)(smem + (w + 8)*P_STRIDE + i*256 + lane*4) = pwB;
    }
  }
  __syncthreads();

  // ---- PV (V-hi only); group g+2 loaded during group g --------------------
  LOADV(1, 1);
  f32x4 ac0 = z4, ac1 = z4;
  #pragma unroll
  for (int g = 0; g < 4; ++g) {
    #pragma unroll
    for (int j = 0; j < 4; ++j) {
      int ksl = g*4 + j;
      bf16x8 pa = *(const bf16x8*)(smem + l15*P_STRIDE + (half*16 + ksl)*64 + l4*16);
      if (j & 1) ac1 = MFMA(pa, vv[g & 1][j], ac1);
      else       ac0 = MFMA(pa, vv[g & 1][j], ac0);
    }
    if (g == 0) LOADV(0, 2);
    if (g == 1) LOADV(1, 3);
  }
  f32x4 a = ac0 + ac1;

  if (half == 1)
    *(f32x4*)(smem + PART_OFF + (f*64 + lane)*16) = a;
  __syncthreads();
  if (half == 0) {
    f32x4 o4 = *(const f32x4*)(smem + PART_OFF + (f*64 + lane)*16);
    #pragma unroll
    for (int r = 0; r < 4; ++r) {
      float val = a[r] + o4[r];
      size_t o = (size_t)(b*1024 + q0 + l4*4 + r) * 1024 + h*64 + f*16 + l15;
      Ath[o] = f2bf(val);
    }
  }
}

// ---------------------------------------------------------------------------
extern "C" void kernel_launch(void* const* d_in, const int* in_sizes, int n_in,
                              void* d_out, int out_size, void* d_ws, size_t ws_size,
                              hipStream_t stream)
{
  const float* q  = (const float*)d_in[0];
  const float* k  = (const float*)d_in[1];
  const float* v  = (const float*)d_in[2];
  const float* wq = (const float*)d_in[3];
  const float* bq = (const float*)d_in[4];
  const float* wk = (const float*)d_in[5];
  const float* bk = (const float*)d_in[6];
  const float* wv = (const float*)d_in[7];
  const float* bv = (const float*)d_in[8];
  const float* wo = (const float*)d_in[9];
  const float* bo = (const float*)d_in[10];
  float* out = (float*)d_out;
  char* ws = (char*)d_ws;
  if (ws_size < (64ull << 20)) return;  // need 64 MB scratch

  presplit_kernel<<<dim3(2048, 7), 256, 0, stream>>>(q, k, v, wq, wk, wv, wo, ws);
  proj_kernel<<<384, 512, 0, stream>>>(ws, bq, bk, bv);
  attn_kernel<<<2048, 512, 0, stream>>>(ws);
  final_kernel<<<512, 256, 0, stream>>>(ws, bo, out);
}